// Round 11
// baseline (4753.841 us; speedup 1.0000x reference)
//
#include <hip/hip_runtime.h>

#define NPTS 4096
#define NPT  1024
#define BATCH 16

// ---------------------------------------------------------------------------
// DPP helpers: VALU-speed cross-lane max-reduce on a packed u64 key
// (float_bits(dist)<<32)|~idx. dist>=0 -> float bits monotone; ~idx breaks
// ties toward the smaller index (== jnp.argmax first-max).
// ---------------------------------------------------------------------------
template <int CTRL>
__device__ __forceinline__ void dpp_keymax_xyz(unsigned long long& key,
                                               float& x, float& y, float& z)
{
    const int klo = (int)(unsigned int)key;
    const int khi = (int)(unsigned int)(key >> 32);
    const int nlo = __builtin_amdgcn_update_dpp(0, klo, CTRL, 0xF, 0xF, false);
    const int nhi = __builtin_amdgcn_update_dpp(0, khi, CTRL, 0xF, 0xF, false);
    const int nx  = __builtin_amdgcn_update_dpp(0, __float_as_int(x), CTRL, 0xF, 0xF, false);
    const int ny  = __builtin_amdgcn_update_dpp(0, __float_as_int(y), CTRL, 0xF, 0xF, false);
    const int nz  = __builtin_amdgcn_update_dpp(0, __float_as_int(z), CTRL, 0xF, 0xF, false);
    const unsigned long long ok =
        ((unsigned long long)(unsigned int)nhi << 32) | (unsigned int)nlo;
    const bool gt = ok > key;
    key = gt ? ok : key;
    x = gt ? __int_as_float(nx) : x;
    y = gt ? __int_as_float(ny) : y;
    z = gt ? __int_as_float(nz) : z;
}

// ---------------------------------------------------------------------------
// Farthest point sampling (round-10 form: coords travel with the key through
// every reduction stage; no winner-dependent LDS read on the critical path).
// Distance math identical to reference (no-FMA ((dx*dx+dy*dy)+dz*dz), fminf).
// ---------------------------------------------------------------------------
__global__ __launch_bounds__(256) void fps_kernel(
    const float* __restrict__ xyz,
    float* __restrict__ out_nxyz,
    float* __restrict__ out_idxf)
{
    __shared__ float sx[NPTS], sy[NPTS], sz[NPTS];
    __shared__ float4 pr0[2][4];    // {key_lo, key_hi, x, y} per wave
    __shared__ float  pr1[2][4];    // z per wave
    __shared__ int sidx[NPT];

    const int tid  = threadIdx.x;
    const int b    = blockIdx.x;
    const int lane = tid & 63;
    const int wid  = tid >> 6;

    const float* bx = xyz + (size_t)b * NPTS * 3;
    for (int p = tid; p < NPTS; p += 256) {
        sx[p] = bx[3 * p];
        sy[p] = bx[3 * p + 1];
        sz[p] = bx[3 * p + 2];
    }
    if (tid == 0) sidx[0] = 0;
    __syncthreads();

    float rx[16], ry[16], rz[16], dist[16];
#pragma unroll
    for (int j = 0; j < 16; ++j) {
        const int p = tid + j * 256;
        rx[j] = sx[p];
        ry[j] = sy[p];
        rz[j] = sz[p];
        dist[j] = 1e10f;
    }

    float lx = sx[0], ly = sy[0], lz = sz[0];

    for (int step = 1; step < NPT; ++step) {
        float bv = -1.0f;
        int   bp = 0;
        float bxl = 0.0f, byl = 0.0f, bzl = 0.0f;
#pragma unroll
        for (int j = 0; j < 16; ++j) {
            const int p = tid + j * 256;
            const float dx = __fsub_rn(rx[j], lx);
            const float dy = __fsub_rn(ry[j], ly);
            const float dz = __fsub_rn(rz[j], lz);
            const float d  = __fadd_rn(__fadd_rn(__fmul_rn(dx, dx), __fmul_rn(dy, dy)),
                                       __fmul_rn(dz, dz));
            const float nd = fminf(dist[j], d);
            dist[j] = nd;
            const bool gt = nd > bv;
            bv  = gt ? nd    : bv;
            bp  = gt ? p     : bp;
            bxl = gt ? rx[j] : bxl;
            byl = gt ? ry[j] : byl;
            bzl = gt ? rz[j] : bzl;
        }
        unsigned long long key =
            ((unsigned long long)__float_as_uint(bv) << 32) |
            (unsigned int)(~bp);

        dpp_keymax_xyz<0x111>(key, bxl, byl, bzl);   // row_shr:1
        dpp_keymax_xyz<0x112>(key, bxl, byl, bzl);   // row_shr:2
        dpp_keymax_xyz<0x114>(key, bxl, byl, bzl);   // row_shr:4
        dpp_keymax_xyz<0x118>(key, bxl, byl, bzl);   // row_shr:8
        dpp_keymax_xyz<0x142>(key, bxl, byl, bzl);   // row_bcast15
        dpp_keymax_xyz<0x143>(key, bxl, byl, bzl);   // row_bcast31 -> lane63

        const int par = step & 1;
        if (lane == 63) {
            pr0[par][wid] = make_float4(
                __int_as_float((int)(unsigned int)key),
                __int_as_float((int)(unsigned int)(key >> 32)),
                bxl, byl);
            pr1[par][wid] = bzl;
        }
        __syncthreads();

        const float4 r   = pr0[par][lane & 3];
        const float  rzz = pr1[par][lane & 3];
        unsigned long long gkey =
            ((unsigned long long)(unsigned int)__float_as_int(r.y) << 32) |
            (unsigned int)__float_as_int(r.x);
        float gx = r.z, gy = r.w, gz = rzz;
        dpp_keymax_xyz<0xB1>(gkey, gx, gy, gz);   // quad_perm xor1
        dpp_keymax_xyz<0x4E>(gkey, gx, gy, gz);   // quad_perm xor2

        lx = gx; ly = gy; lz = gz;
        if (tid == 0) sidx[step] = (int)(~(unsigned int)gkey);
    }
    __syncthreads();

    for (int s = tid; s < NPT; s += 256) {
        const int ix = sidx[s];
        out_idxf[b * NPT + s] = (float)ix;
        out_nxyz[(size_t)(b * NPT + s) * 3 + 0] = sx[ix];
        out_nxyz[(size_t)(b * NPT + s) * 3 + 1] = sy[ix];
        out_nxyz[(size_t)(b * NPT + s) * 3 + 2] = sz[ix];
    }
}

// ---------------------------------------------------------------------------
// Final layer: output channels in chunks of CH inside a ROLLED chunk loop.
// ---------------------------------------------------------------------------
template <int CIN, int FOUT, int CH, int K>
__device__ __forceinline__ void dense_pool_store(const float* __restrict__ W,
                                                 const float* __restrict__ in,
                                                 int k, float* __restrict__ outp)
{
#pragma unroll 1
    for (int ch = 0; ch < FOUT / CH; ++ch) {
        const float* __restrict__ Wc = W + ch * CH;
        float acc[CH];
#pragma unroll
        for (int j = 0; j < CH; ++j) acc[j] = 0.0f;
#pragma unroll
        for (int c = 0; c < CIN; ++c) {
            const float xc = in[c];
#pragma unroll
            for (int j = 0; j < CH; ++j)
                acc[j] = fmaf(xc, Wc[c * FOUT + j], acc[j]);
        }
#pragma unroll
        for (int j = 0; j < CH; ++j) acc[j] = fmaxf(acc[j], 0.0f);
#pragma unroll
        for (int off = 1; off < K; off <<= 1) {
#pragma unroll
            for (int j = 0; j < CH; ++j)
                acc[j] = fmaxf(acc[j], __shfl_xor(acc[j], off));
        }
        if (k == 0) {
            float4* o = (float4*)(outp + ch * CH);
#pragma unroll
            for (int j = 0; j < CH / 4; ++j)
                o[j] = make_float4(acc[4 * j + 0], acc[4 * j + 1],
                                   acc[4 * j + 2], acc[4 * j + 3]);
        }
    }
}

// ---------------------------------------------------------------------------
// Per-scale: ball query + gather + 3-layer MLP + max-pool (round-7 fused
// stream). NEW: weight pointers carry a runtime-zero, LANE-DEPENDENT offset
// (zero*(tid+1), zero==0 at runtime). This breaks the compiler's uniformity
// proof so weight reads become VECTOR global_load_dwordx4 (TA coalesces the
// all-lanes-same-address access to one 16B fetch + broadcast): deep vmcnt
// pipelining + 32KB vector L1, instead of s_load batches squeezed through
// ~100 SGPRs with lgkmcnt drains (the ~64% stall measured in r7/r10 --
// corrected VALUBusy ~36% == the FMA-issue floor 262/750).
// Same values, same c-ascending fmaf chains -> bit-identical output.
// ---------------------------------------------------------------------------
template <int K, int F0, int F1, int F2, int CH_OFF, int NT>
__global__ __launch_bounds__(NT, 1) void sa_kernel(
    const float* __restrict__ xyz,
    const float* __restrict__ points,
    const float* __restrict__ newxyz,
    const float* __restrict__ w0_,
    const float* __restrict__ w1_,
    const float* __restrict__ w2_,
    float* __restrict__ out1,
    float r2, int zero)
{
    constexpr int QPW = 64 / K;
    constexpr int NW  = NT / 64;
    constexpr unsigned long long KMASK =
        (K == 64) ? ~0ULL : ((1ULL << K) - 1ULL);

    __shared__ int slist[NT];

    const int tid  = threadIdx.x;
    const int lane = tid & 63;
    const int wid  = tid >> 6;
    const int k    = lane & (K - 1);
    const int qsub = lane / K;
    const int qid  = (blockIdx.x * NW + wid) * QPW + qsub;
    const int b    = qid >> 10;

    // runtime-zero divergent offset: forces vector (non-scalar) weight loads
    const int zoff = zero * (tid + 1);
    const float* __restrict__ w0 = w0_ + zoff;
    const float* __restrict__ w1 = w1_ + zoff;
    const float* __restrict__ w2 = w2_ + zoff;

    const float qx = newxyz[(size_t)qid * 3 + 0];
    const float qy = newxyz[(size_t)qid * 3 + 1];
    const float qz = newxyz[(size_t)qid * 3 + 2];
    const float* bxyz = xyz + (size_t)b * NPTS * 3;

    // ---- ball query: first K in-ball indices in ascending order ----
    int cnt = 0;
    const int gbase = (wid * QPW + qsub) * K;
    for (int c0 = 0; c0 < NPTS; c0 += K) {
        bool hit = false;
        const int p = c0 + k;
        if (cnt < K) {
            const float dx = __fsub_rn(qx, bxyz[3 * p]);
            const float dy = __fsub_rn(qy, bxyz[3 * p + 1]);
            const float dz = __fsub_rn(qz, bxyz[3 * p + 2]);
            const float d2 = __fadd_rn(__fadd_rn(__fmul_rn(dx, dx), __fmul_rn(dy, dy)),
                                       __fmul_rn(dz, dz));
            hit = d2 < r2;
        }
        const unsigned long long bal = __ballot(hit);
        const unsigned long long gm  = (bal >> (qsub * K)) & KMASK;
        const int pre = __popcll(gm & ((1ULL << k) - 1ULL));
        const int pos = cnt + pre;
        if (hit && pos < K) slist[gbase + pos] = p;
        cnt = min(cnt + (int)__popcll(gm), K);
        if (__all(cnt >= K)) break;
    }
    const int nbr = slist[gbase + ((k < cnt) ? k : 0)];

    // ---- gather: 16 point features + 3 relative xyz into REGISTERS ----
    float a0r[19];
    {
        const float4* prow = (const float4*)(points + ((size_t)b * NPTS + nbr) * 16);
        const float4 p0 = prow[0], p1 = prow[1], p2 = prow[2], p3 = prow[3];
        a0r[0]  = p0.x; a0r[1]  = p0.y; a0r[2]  = p0.z; a0r[3]  = p0.w;
        a0r[4]  = p1.x; a0r[5]  = p1.y; a0r[6]  = p1.z; a0r[7]  = p1.w;
        a0r[8]  = p2.x; a0r[9]  = p2.y; a0r[10] = p2.z; a0r[11] = p2.w;
        a0r[12] = p3.x; a0r[13] = p3.y; a0r[14] = p3.z; a0r[15] = p3.w;
        a0r[16] = __fsub_rn(bxyz[3 * nbr],     qx);
        a0r[17] = __fsub_rn(bxyz[3 * nbr + 1], qy);
        a0r[18] = __fsub_rn(bxyz[3 * nbr + 2], qz);
    }

    // ---- fused layer1 + layer2 stream ----
    float acc1[F1];
#pragma unroll
    for (int f = 0; f < F1; ++f) acc1[f] = 0.0f;

#pragma unroll 1
    for (int ch = 0; ch < F0 / 16; ++ch) {
        const float* __restrict__ W0c = w0 + ch * 16;
        float t[16];
#pragma unroll
        for (int j = 0; j < 16; ++j) t[j] = 0.0f;
#pragma unroll
        for (int c = 0; c < 19; ++c) {
            const float xc = a0r[c];
#pragma unroll
            for (int j = 0; j < 16; ++j)
                t[j] = fmaf(xc, W0c[c * F0 + j], t[j]);
        }
#pragma unroll
        for (int j = 0; j < 16; ++j) t[j] = fmaxf(t[j], 0.0f);

        const float* __restrict__ W1c = w1 + (size_t)ch * 16 * F1;
#pragma unroll
        for (int i = 0; i < 16; ++i) {
            const float xi = t[i];
#pragma unroll
            for (int f = 0; f < F1; ++f)
                acc1[f] = fmaf(xi, W1c[i * F1 + f], acc1[f]);
        }
    }
#pragma unroll
    for (int f = 0; f < F1; ++f) acc1[f] = fmaxf(acc1[f], 0.0f);

    dense_pool_store<F1, F2, 16, K>(w2, acc1, k,
                                    out1 + (size_t)qid * 320 + CH_OFF);
}

// ---------------------------------------------------------------------------
extern "C" void kernel_launch(void* const* d_in, const int* in_sizes, int n_in,
                              void* d_out, int out_size, void* d_ws, size_t ws_size,
                              hipStream_t stream)
{
    const float* xyz    = (const float*)d_in[0];
    const float* points = (const float*)d_in[1];
    const float* w00 = (const float*)d_in[2];
    const float* w01 = (const float*)d_in[3];
    const float* w02 = (const float*)d_in[4];
    const float* w10 = (const float*)d_in[5];
    const float* w11 = (const float*)d_in[6];
    const float* w12 = (const float*)d_in[7];
    const float* w20 = (const float*)d_in[8];
    const float* w21 = (const float*)d_in[9];
    const float* w22 = (const float*)d_in[10];

    float* out       = (float*)d_out;
    float* out_nxyz  = out;                       // 16*1024*3   = 49152
    float* out_feat  = out + 49152;               // 16*1024*320 = 5242880
    float* out_idxf  = out + 49152 + 5242880;     // 16*1024     = 16384

    const int zero = (n_in > 4096) ? 1 : 0;       // always 0 (n_in == 11)

    fps_kernel<<<BATCH, 256, 0, stream>>>(xyz, out_nxyz, out_idxf);

    // scale 0: r=0.1, K=16, MLP 19->32->32->64, CH_OFF 0
    sa_kernel<16, 32, 32, 64, 0, 256><<<1024, 256, 0, stream>>>(
        xyz, points, out_nxyz, w00, w01, w02, out_feat, (float)(0.1 * 0.1), zero);
    // scale 1: r=0.2, K=32, MLP 19->64->64->128, CH_OFF 64
    sa_kernel<32, 64, 64, 128, 64, 128><<<4096, 128, 0, stream>>>(
        xyz, points, out_nxyz, w10, w11, w12, out_feat, (float)(0.2 * 0.2), zero);
    // scale 2: r=0.4, K=64, MLP 19->64->96->128, CH_OFF 192
    sa_kernel<64, 64, 96, 128, 192, 128><<<8192, 128, 0, stream>>>(
        xyz, points, out_nxyz, w20, w21, w22, out_feat, (float)(0.4 * 0.4), zero);
}

// Round 12
// 1207.353 us; speedup vs baseline: 3.9374x; 3.9374x over previous
//
#include <hip/hip_runtime.h>

#define NPTS 4096
#define NPT  1024
#define BATCH 16

typedef __attribute__((ext_vector_type(8))) short bf16x8;
typedef __attribute__((ext_vector_type(4))) float f32x4;

__device__ __forceinline__ unsigned short f2bf(float f) {
    unsigned u = __float_as_uint(f);
    u += 0x7fffu + ((u >> 16) & 1u);      // RNE; finite inputs only
    return (unsigned short)(u >> 16);
}

// ---------------------------------------------------------------------------
// DPP helper: packed u64 keymax carrying coords (FPS reduction).
// ---------------------------------------------------------------------------
template <int CTRL>
__device__ __forceinline__ void dpp_keymax_xyz(unsigned long long& key,
                                               float& x, float& y, float& z)
{
    const int klo = (int)(unsigned int)key;
    const int khi = (int)(unsigned int)(key >> 32);
    const int nlo = __builtin_amdgcn_update_dpp(0, klo, CTRL, 0xF, 0xF, false);
    const int nhi = __builtin_amdgcn_update_dpp(0, khi, CTRL, 0xF, 0xF, false);
    const int nx  = __builtin_amdgcn_update_dpp(0, __float_as_int(x), CTRL, 0xF, 0xF, false);
    const int ny  = __builtin_amdgcn_update_dpp(0, __float_as_int(y), CTRL, 0xF, 0xF, false);
    const int nz  = __builtin_amdgcn_update_dpp(0, __float_as_int(z), CTRL, 0xF, 0xF, false);
    const unsigned long long ok =
        ((unsigned long long)(unsigned int)nhi << 32) | (unsigned int)nlo;
    const bool gt = ok > key;
    key = gt ? ok : key;
    x = gt ? __int_as_float(nx) : x;
    y = gt ? __int_as_float(ny) : y;
    z = gt ? __int_as_float(nz) : z;
}

// ---------------------------------------------------------------------------
// Farthest point sampling (bit-exact, unchanged from round 10).
// ---------------------------------------------------------------------------
__global__ __launch_bounds__(256) void fps_kernel(
    const float* __restrict__ xyz,
    float* __restrict__ out_nxyz,
    float* __restrict__ out_idxf)
{
    __shared__ float sx[NPTS], sy[NPTS], sz[NPTS];
    __shared__ float4 pr0[2][4];
    __shared__ float  pr1[2][4];
    __shared__ int sidx[NPT];

    const int tid  = threadIdx.x;
    const int b    = blockIdx.x;
    const int lane = tid & 63;
    const int wid  = tid >> 6;

    const float* bx = xyz + (size_t)b * NPTS * 3;
    for (int p = tid; p < NPTS; p += 256) {
        sx[p] = bx[3 * p];
        sy[p] = bx[3 * p + 1];
        sz[p] = bx[3 * p + 2];
    }
    if (tid == 0) sidx[0] = 0;
    __syncthreads();

    float rx[16], ry[16], rz[16], dist[16];
#pragma unroll
    for (int j = 0; j < 16; ++j) {
        const int p = tid + j * 256;
        rx[j] = sx[p];
        ry[j] = sy[p];
        rz[j] = sz[p];
        dist[j] = 1e10f;
    }

    float lx = sx[0], ly = sy[0], lz = sz[0];

    for (int step = 1; step < NPT; ++step) {
        float bv = -1.0f;
        int   bp = 0;
        float bxl = 0.0f, byl = 0.0f, bzl = 0.0f;
#pragma unroll
        for (int j = 0; j < 16; ++j) {
            const int p = tid + j * 256;
            const float dx = __fsub_rn(rx[j], lx);
            const float dy = __fsub_rn(ry[j], ly);
            const float dz = __fsub_rn(rz[j], lz);
            const float d  = __fadd_rn(__fadd_rn(__fmul_rn(dx, dx), __fmul_rn(dy, dy)),
                                       __fmul_rn(dz, dz));
            const float nd = fminf(dist[j], d);
            dist[j] = nd;
            const bool gt = nd > bv;
            bv  = gt ? nd    : bv;
            bp  = gt ? p     : bp;
            bxl = gt ? rx[j] : bxl;
            byl = gt ? ry[j] : byl;
            bzl = gt ? rz[j] : bzl;
        }
        unsigned long long key =
            ((unsigned long long)__float_as_uint(bv) << 32) |
            (unsigned int)(~bp);

        dpp_keymax_xyz<0x111>(key, bxl, byl, bzl);   // row_shr:1
        dpp_keymax_xyz<0x112>(key, bxl, byl, bzl);   // row_shr:2
        dpp_keymax_xyz<0x114>(key, bxl, byl, bzl);   // row_shr:4
        dpp_keymax_xyz<0x118>(key, bxl, byl, bzl);   // row_shr:8
        dpp_keymax_xyz<0x142>(key, bxl, byl, bzl);   // row_bcast15
        dpp_keymax_xyz<0x143>(key, bxl, byl, bzl);   // row_bcast31 -> lane63

        const int par = step & 1;
        if (lane == 63) {
            pr0[par][wid] = make_float4(
                __int_as_float((int)(unsigned int)key),
                __int_as_float((int)(unsigned int)(key >> 32)),
                bxl, byl);
            pr1[par][wid] = bzl;
        }
        __syncthreads();

        const float4 r   = pr0[par][lane & 3];
        const float  rzz = pr1[par][lane & 3];
        unsigned long long gkey =
            ((unsigned long long)(unsigned int)__float_as_int(r.y) << 32) |
            (unsigned int)__float_as_int(r.x);
        float gx = r.z, gy = r.w, gz = rzz;
        dpp_keymax_xyz<0xB1>(gkey, gx, gy, gz);   // quad_perm xor1
        dpp_keymax_xyz<0x4E>(gkey, gx, gy, gz);   // quad_perm xor2

        lx = gx; ly = gy; lz = gz;
        if (tid == 0) sidx[step] = (int)(~(unsigned int)gkey);
    }
    __syncthreads();

    for (int s = tid; s < NPT; s += 256) {
        const int ix = sidx[s];
        out_idxf[b * NPT + s] = (float)ix;
        out_nxyz[(size_t)(b * NPT + s) * 3 + 0] = sx[ix];
        out_nxyz[(size_t)(b * NPT + s) * 3 + 1] = sy[ix];
        out_nxyz[(size_t)(b * NPT + s) * 3 + 2] = sz[ix];
    }
}

// ---------------------------------------------------------------------------
// MFMA SA kernel for K in {32,64}. Block = 256 thr = 4 waves; each wave owns
// 64 neighbor-rows = QW queries (QW = 64/K). Activations in LDS bf16,
// [64 rows][stride 104] per wave (16B-aligned ds_read_b128 A-frags, 2-way-free
// banks). Weights read from global fp32 per B-fragment + RNE cvt (L1-hot).
// MFMA 16x16x32 bf16, fp32 accum. Layouts: A elem j = A[lane&15][(lane>>4)*8+j]
// (rows within m-tile), B elem j = B[(lane>>4)*8+j][lane&15], C reg r =
// C[(lane>>4)*4+r][lane&15] (m89-verified). Max-pool in-register via
// shfl_xor 16/32 + per-query m-tile fmax. Ball query identical fp32 to r7.
// ---------------------------------------------------------------------------
template <int K, int F0, int F1, int F2, int CH_OFF>
__global__ __launch_bounds__(256) void sa_mfma_kernel(
    const float* __restrict__ xyz,
    const float* __restrict__ points,
    const float* __restrict__ newxyz,
    const float* __restrict__ w0,
    const float* __restrict__ w1,
    const float* __restrict__ w2,
    float* __restrict__ out1,
    float r2)
{
    constexpr int TPQ = K / 16;        // m-tiles per query
    constexpr int QW  = 4 / TPQ;       // queries per wave
    constexpr int KF1 = F0 / 32;       // k-frags layer2
    constexpr int KF2 = F1 / 32;       // k-frags layer3
    constexpr int NT0 = F0 / 16, NT1 = F1 / 16, NT2 = F2 / 16;
    constexpr int NH1 = NT1 / 2;       // layer2 n-tiles per half
    constexpr int STRIDE = 104;        // bf16 elems per row (208B, 13x16B)
    constexpr unsigned long long KMASK =
        (K == 64) ? ~0ULL : ((1ULL << K) - 1ULL);

    __shared__ __attribute__((aligned(16))) unsigned short act[4][64 * STRIDE];
    __shared__ int slist[256];

    const int tid  = threadIdx.x;
    const int lane = tid & 63;
    const int wid  = tid >> 6;
    const int k    = lane & (K - 1);
    const int qsub = lane / K;
    const int qid  = (blockIdx.x * 4 + wid) * QW + qsub;
    const int b    = qid >> 10;
    unsigned short* __restrict__ A = act[wid];

    const float qx = newxyz[(size_t)qid * 3 + 0];
    const float qy = newxyz[(size_t)qid * 3 + 1];
    const float qz = newxyz[(size_t)qid * 3 + 2];
    const float* bxyz = xyz + (size_t)b * NPTS * 3;

    // ---- ball query (bit-exact fp32, first-K ascending) ----
    int cnt = 0;
    const int gbase = wid * 64 + qsub * K;
    for (int c0 = 0; c0 < NPTS; c0 += K) {
        bool hit = false;
        const int p = c0 + k;
        if (cnt < K) {
            const float dx = __fsub_rn(qx, bxyz[3 * p]);
            const float dy = __fsub_rn(qy, bxyz[3 * p + 1]);
            const float dz = __fsub_rn(qz, bxyz[3 * p + 2]);
            const float d2 = __fadd_rn(__fadd_rn(__fmul_rn(dx, dx), __fmul_rn(dy, dy)),
                                       __fmul_rn(dz, dz));
            hit = d2 < r2;
        }
        const unsigned long long bal = __ballot(hit);
        const unsigned long long gm  = (bal >> (qsub * K)) & KMASK;
        const int pre = __popcll(gm & ((1ULL << k) - 1ULL));
        const int pos = cnt + pre;
        if (hit && pos < K) slist[gbase + pos] = p;
        cnt = min(cnt + (int)__popcll(gm), K);
        if (__all(cnt >= K)) break;
    }
    const int nbr = slist[gbase + ((k < cnt) ? k : 0)];

    // ---- gather -> LDS bf16 row (cols 0-15 feats, 16-18 relxyz, 19-31 zero) ----
    {
        unsigned short e[32];
        const float4* prow = (const float4*)(points + ((size_t)b * NPTS + nbr) * 16);
        const float4 p0 = prow[0], p1 = prow[1], p2 = prow[2], p3 = prow[3];
        e[0]  = f2bf(p0.x); e[1]  = f2bf(p0.y); e[2]  = f2bf(p0.z); e[3]  = f2bf(p0.w);
        e[4]  = f2bf(p1.x); e[5]  = f2bf(p1.y); e[6]  = f2bf(p1.z); e[7]  = f2bf(p1.w);
        e[8]  = f2bf(p2.x); e[9]  = f2bf(p2.y); e[10] = f2bf(p2.z); e[11] = f2bf(p2.w);
        e[12] = f2bf(p3.x); e[13] = f2bf(p3.y); e[14] = f2bf(p3.z); e[15] = f2bf(p3.w);
        e[16] = f2bf(__fsub_rn(bxyz[3 * nbr],     qx));
        e[17] = f2bf(__fsub_rn(bxyz[3 * nbr + 1], qy));
        e[18] = f2bf(__fsub_rn(bxyz[3 * nbr + 2], qz));
#pragma unroll
        for (int j = 19; j < 32; ++j) e[j] = 0;
        unsigned int* dst = (unsigned int*)&A[lane * STRIDE];
#pragma unroll
        for (int j = 0; j < 16; ++j)
            dst[j] = ((unsigned int)e[2 * j + 1] << 16) | e[2 * j];
    }
    __syncthreads();

    const int lr = lane & 15;   // lane row/col within tile
    const int lg = lane >> 4;   // k/row group

    // ---- layer 1: [64x32] @ [32(19)xF0] ----
    bf16x8 a1[4];
#pragma unroll
    for (int m = 0; m < 4; ++m)
        a1[m] = *(const bf16x8*)&A[(m * 16 + lr) * STRIDE + lg * 8];

    bf16x8 b1[NT0];
#pragma unroll
    for (int n = 0; n < NT0; ++n) {
#pragma unroll
        for (int j = 0; j < 8; ++j) {
            const int kk = lg * 8 + j;
            const int kc = (kk < 19) ? kk : 18;
            const float v = w0[kc * F0 + n * 16 + lr];
            b1[n][j] = (kk < 19) ? (short)f2bf(v) : (short)0;
        }
    }
    f32x4 c1[4][NT0];
#pragma unroll
    for (int m = 0; m < 4; ++m)
#pragma unroll
        for (int n = 0; n < NT0; ++n) {
            f32x4 z = {0.0f, 0.0f, 0.0f, 0.0f};
            c1[m][n] = __builtin_amdgcn_mfma_f32_16x16x32_bf16(a1[m], b1[n], z, 0, 0, 0);
        }
    __syncthreads();
#pragma unroll
    for (int m = 0; m < 4; ++m)
#pragma unroll
        for (int n = 0; n < NT0; ++n)
#pragma unroll
            for (int r = 0; r < 4; ++r)
                A[(m * 16 + lg * 4 + r) * STRIDE + n * 16 + lr] =
                    f2bf(fmaxf(c1[m][n][r], 0.0f));
    __syncthreads();

    // ---- layer 2: [64xF0] @ [F0xF1], two n-halves for register pressure ----
    bf16x8 a2[4][KF1];
#pragma unroll
    for (int m = 0; m < 4; ++m)
#pragma unroll
        for (int kf = 0; kf < KF1; ++kf)
            a2[m][kf] = *(const bf16x8*)&A[(m * 16 + lr) * STRIDE + kf * 32 + lg * 8];
    __syncthreads();   // all reads of h0 done before overwriting with h1

#pragma unroll
    for (int half = 0; half < 2; ++half) {
        bf16x8 b2[NH1][KF1];
#pragma unroll
        for (int n = 0; n < NH1; ++n)
#pragma unroll
            for (int kf = 0; kf < KF1; ++kf)
#pragma unroll
                for (int j = 0; j < 8; ++j) {
                    const int kk = kf * 32 + lg * 8 + j;
                    b2[n][kf][j] = (short)f2bf(w1[(size_t)kk * F1 + (half * NH1 + n) * 16 + lr]);
                }
        f32x4 c2[4][NH1];
#pragma unroll
        for (int m = 0; m < 4; ++m)
#pragma unroll
            for (int n = 0; n < NH1; ++n) {
                f32x4 z = {0.0f, 0.0f, 0.0f, 0.0f};
#pragma unroll
                for (int kf = 0; kf < KF1; ++kf)
                    z = __builtin_amdgcn_mfma_f32_16x16x32_bf16(a2[m][kf], b2[n][kf], z, 0, 0, 0);
                c2[m][n] = z;
            }
#pragma unroll
        for (int m = 0; m < 4; ++m)
#pragma unroll
            for (int n = 0; n < NH1; ++n)
#pragma unroll
                for (int r = 0; r < 4; ++r)
                    A[(m * 16 + lg * 4 + r) * STRIDE + (half * NH1 + n) * 16 + lr] =
                        f2bf(fmaxf(c2[m][n][r], 0.0f));
    }
    __syncthreads();

    // ---- layer 3 + relu + max-pool over neighbors + store ----
    bf16x8 a3[4][KF2];
#pragma unroll
    for (int m = 0; m < 4; ++m)
#pragma unroll
        for (int kf = 0; kf < KF2; ++kf)
            a3[m][kf] = *(const bf16x8*)&A[(m * 16 + lr) * STRIDE + kf * 32 + lg * 8];

    const int qbase = (blockIdx.x * 4 + wid) * QW;
#pragma unroll
    for (int n = 0; n < NT2; ++n) {
        bf16x8 b3[KF2];
#pragma unroll
        for (int kf = 0; kf < KF2; ++kf)
#pragma unroll
            for (int j = 0; j < 8; ++j) {
                const int kk = kf * 32 + lg * 8 + j;
                b3[kf][j] = (short)f2bf(w2[(size_t)kk * F2 + n * 16 + lr]);
            }
        float q0 = 0.0f, q1 = 0.0f;
#pragma unroll
        for (int m = 0; m < 4; ++m) {
            f32x4 c = {0.0f, 0.0f, 0.0f, 0.0f};
#pragma unroll
            for (int kf = 0; kf < KF2; ++kf)
                c = __builtin_amdgcn_mfma_f32_16x16x32_bf16(a3[m][kf], b3[kf], c, 0, 0, 0);
            float v = fmaxf(fmaxf(c[0], c[1]), fmaxf(c[2], c[3]));
            v = fmaxf(v, 0.0f);                       // relu then pool == pool then relu
            v = fmaxf(v, __shfl_xor(v, 16));
            v = fmaxf(v, __shfl_xor(v, 32));          // col-max over the m-tile's 16 rows
            if (QW == 1) {
                q0 = fmaxf(q0, v);
            } else {
                if (m < 2) q0 = fmaxf(q0, v); else q1 = fmaxf(q1, v);
            }
        }
        if (lg < QW) {
            const float val = (QW == 2 && lg == 1) ? q1 : q0;
            out1[(size_t)(qbase + lg) * 320 + CH_OFF + n * 16 + lr] = val;
        }
    }
}

// ---------------------------------------------------------------------------
// Round-7 fp32 fused-stream kernel (kept for scale 0, K=16).
// ---------------------------------------------------------------------------
template <int CIN, int FOUT, int CH, int K>
__device__ __forceinline__ void dense_pool_store(const float* __restrict__ W,
                                                 const float* __restrict__ in,
                                                 int k, float* __restrict__ outp)
{
#pragma unroll 1
    for (int ch = 0; ch < FOUT / CH; ++ch) {
        const float* __restrict__ Wc = W + ch * CH;
        float acc[CH];
#pragma unroll
        for (int j = 0; j < CH; ++j) acc[j] = 0.0f;
#pragma unroll
        for (int c = 0; c < CIN; ++c) {
            const float xc = in[c];
#pragma unroll
            for (int j = 0; j < CH; ++j)
                acc[j] = fmaf(xc, Wc[c * FOUT + j], acc[j]);
        }
#pragma unroll
        for (int j = 0; j < CH; ++j) acc[j] = fmaxf(acc[j], 0.0f);
#pragma unroll
        for (int off = 1; off < K; off <<= 1) {
#pragma unroll
            for (int j = 0; j < CH; ++j)
                acc[j] = fmaxf(acc[j], __shfl_xor(acc[j], off));
        }
        if (k == 0) {
            float4* o = (float4*)(outp + ch * CH);
#pragma unroll
            for (int j = 0; j < CH / 4; ++j)
                o[j] = make_float4(acc[4 * j + 0], acc[4 * j + 1],
                                   acc[4 * j + 2], acc[4 * j + 3]);
        }
    }
}

template <int K, int F0, int F1, int F2, int CH_OFF, int NT>
__global__ __launch_bounds__(NT, 1) void sa_kernel(
    const float* __restrict__ xyz,
    const float* __restrict__ points,
    const float* __restrict__ newxyz,
    const float* __restrict__ w0,
    const float* __restrict__ w1,
    const float* __restrict__ w2,
    float* __restrict__ out1,
    float r2)
{
    constexpr int QPW = 64 / K;
    constexpr int NW  = NT / 64;
    constexpr unsigned long long KMASK =
        (K == 64) ? ~0ULL : ((1ULL << K) - 1ULL);

    __shared__ int slist[NT];

    const int tid  = threadIdx.x;
    const int lane = tid & 63;
    const int wid  = tid >> 6;
    const int k    = lane & (K - 1);
    const int qsub = lane / K;
    const int qid  = (blockIdx.x * NW + wid) * QPW + qsub;
    const int b    = qid >> 10;

    const float qx = newxyz[(size_t)qid * 3 + 0];
    const float qy = newxyz[(size_t)qid * 3 + 1];
    const float qz = newxyz[(size_t)qid * 3 + 2];
    const float* bxyz = xyz + (size_t)b * NPTS * 3;

    int cnt = 0;
    const int gbase = (wid * QPW + qsub) * K;
    for (int c0 = 0; c0 < NPTS; c0 += K) {
        bool hit = false;
        const int p = c0 + k;
        if (cnt < K) {
            const float dx = __fsub_rn(qx, bxyz[3 * p]);
            const float dy = __fsub_rn(qy, bxyz[3 * p + 1]);
            const float dz = __fsub_rn(qz, bxyz[3 * p + 2]);
            const float d2 = __fadd_rn(__fadd_rn(__fmul_rn(dx, dx), __fmul_rn(dy, dy)),
                                       __fmul_rn(dz, dz));
            hit = d2 < r2;
        }
        const unsigned long long bal = __ballot(hit);
        const unsigned long long gm  = (bal >> (qsub * K)) & KMASK;
        const int pre = __popcll(gm & ((1ULL << k) - 1ULL));
        const int pos = cnt + pre;
        if (hit && pos < K) slist[gbase + pos] = p;
        cnt = min(cnt + (int)__popcll(gm), K);
        if (__all(cnt >= K)) break;
    }
    const int nbr = slist[gbase + ((k < cnt) ? k : 0)];

    float a0r[19];
    {
        const float4* prow = (const float4*)(points + ((size_t)b * NPTS + nbr) * 16);
        const float4 p0 = prow[0], p1 = prow[1], p2 = prow[2], p3 = prow[3];
        a0r[0]  = p0.x; a0r[1]  = p0.y; a0r[2]  = p0.z; a0r[3]  = p0.w;
        a0r[4]  = p1.x; a0r[5]  = p1.y; a0r[6]  = p1.z; a0r[7]  = p1.w;
        a0r[8]  = p2.x; a0r[9]  = p2.y; a0r[10] = p2.z; a0r[11] = p2.w;
        a0r[12] = p3.x; a0r[13] = p3.y; a0r[14] = p3.z; a0r[15] = p3.w;
        a0r[16] = __fsub_rn(bxyz[3 * nbr],     qx);
        a0r[17] = __fsub_rn(bxyz[3 * nbr + 1], qy);
        a0r[18] = __fsub_rn(bxyz[3 * nbr + 2], qz);
    }

    float acc1[F1];
#pragma unroll
    for (int f = 0; f < F1; ++f) acc1[f] = 0.0f;

#pragma unroll 1
    for (int ch = 0; ch < F0 / 16; ++ch) {
        const float* __restrict__ W0c = w0 + ch * 16;
        float t[16];
#pragma unroll
        for (int j = 0; j < 16; ++j) t[j] = 0.0f;
#pragma unroll
        for (int c = 0; c < 19; ++c) {
            const float xc = a0r[c];
#pragma unroll
            for (int j = 0; j < 16; ++j)
                t[j] = fmaf(xc, W0c[c * F0 + j], t[j]);
        }
#pragma unroll
        for (int j = 0; j < 16; ++j) t[j] = fmaxf(t[j], 0.0f);

        const float* __restrict__ W1c = w1 + (size_t)ch * 16 * F1;
#pragma unroll
        for (int i = 0; i < 16; ++i) {
            const float xi = t[i];
#pragma unroll
            for (int f = 0; f < F1; ++f)
                acc1[f] = fmaf(xi, W1c[i * F1 + f], acc1[f]);
        }
    }
#pragma unroll
    for (int f = 0; f < F1; ++f) acc1[f] = fmaxf(acc1[f], 0.0f);

    dense_pool_store<F1, F2, 16, K>(w2, acc1, k,
                                    out1 + (size_t)qid * 320 + CH_OFF);
}

// ---------------------------------------------------------------------------
extern "C" void kernel_launch(void* const* d_in, const int* in_sizes, int n_in,
                              void* d_out, int out_size, void* d_ws, size_t ws_size,
                              hipStream_t stream)
{
    const float* xyz    = (const float*)d_in[0];
    const float* points = (const float*)d_in[1];
    const float* w00 = (const float*)d_in[2];
    const float* w01 = (const float*)d_in[3];
    const float* w02 = (const float*)d_in[4];
    const float* w10 = (const float*)d_in[5];
    const float* w11 = (const float*)d_in[6];
    const float* w12 = (const float*)d_in[7];
    const float* w20 = (const float*)d_in[8];
    const float* w21 = (const float*)d_in[9];
    const float* w22 = (const float*)d_in[10];

    float* out       = (float*)d_out;
    float* out_nxyz  = out;                       // 16*1024*3   = 49152
    float* out_feat  = out + 49152;               // 16*1024*320 = 5242880
    float* out_idxf  = out + 49152 + 5242880;     // 16*1024     = 16384

    fps_kernel<<<BATCH, 256, 0, stream>>>(xyz, out_nxyz, out_idxf);

    // scale 0: r=0.1, K=16, MLP 19->32->32->64, CH_OFF 0 (fp32 path)
    sa_kernel<16, 32, 32, 64, 0, 256><<<1024, 256, 0, stream>>>(
        xyz, points, out_nxyz, w00, w01, w02, out_feat, (float)(0.1 * 0.1));
    // scale 1: r=0.2, K=32, MLP 19->64->64->128, CH_OFF 64 (MFMA, 8 q/block)
    sa_mfma_kernel<32, 64, 64, 128, 64><<<2048, 256, 0, stream>>>(
        xyz, points, out_nxyz, w10, w11, w12, out_feat, (float)(0.2 * 0.2));
    // scale 2: r=0.4, K=64, MLP 19->64->96->128, CH_OFF 192 (MFMA, 4 q/block)
    sa_mfma_kernel<64, 64, 96, 128, 192><<<4096, 256, 0, stream>>>(
        xyz, points, out_nxyz, w20, w21, w22, out_feat, (float)(0.4 * 0.4));
}